// Round 1
// baseline (1539.981 us; speedup 1.0000x reference)
//
#include <hip/hip_runtime.h>

typedef unsigned short u16;
typedef __attribute__((ext_vector_type(8))) short short8;   // 8 x bf16 frag (4 VGPRs)
typedef __attribute__((ext_vector_type(4))) float floatx4;  // MFMA accumulator

#define MFMA16(a, b, c) __builtin_amdgcn_mfma_f32_16x16x32_bf16(a, b, c, 0, 0, 0)

// Problem constants
#define BB 16
#define KK 1024
#define NH 1024
#define HD 8
#define DK 128
#define MM (BB * KK)          // 16384 rows of flattened activations
#define ATT_OFF 16777216      // atted elems (16*1024*1024) before att in d_out

__device__ __forceinline__ u16 f2bf(float x) {  // RNE f32 -> bf16
  unsigned u = __builtin_bit_cast(unsigned, x);
  u += 0x7fffu + ((u >> 16) & 1u);
  return (u16)(u >> 16);
}

// ---------------- weight transpose+cast: in f32 [1024][1024] -> out bf16 [n][k] ----
__global__ __launch_bounds__(256) void tr_w(const float* __restrict__ in,
                                            u16* __restrict__ out) {
  __shared__ u16 t[32][36];
  const int tid = threadIdx.x;
  const int bx = blockIdx.x * 32;  // n base
  const int by = blockIdx.y * 32;  // k base
  const int r = tid >> 3, c4 = (tid & 7) * 4;
  float4 f = *(const float4*)(in + (size_t)(by + r) * 1024 + bx + c4);
  t[r][c4 + 0] = f2bf(f.x);
  t[r][c4 + 1] = f2bf(f.y);
  t[r][c4 + 2] = f2bf(f.z);
  t[r][c4 + 3] = f2bf(f.w);
  __syncthreads();
  union { u16 u[4]; uint2 v; } p;
#pragma unroll
  for (int i = 0; i < 4; i++) p.u[i] = t[c4 + i][r];
  *(uint2*)(out + (size_t)(bx + r) * 1024 + by + c4) = p.v;  // out[n][k] = in[k][n]
}

// ---------------- vv head transpose: vvb bf16 [b,i,h*128+d] -> vvT [bh][d][i] -------
__global__ __launch_bounds__(256) void tr_head(const u16* __restrict__ vvb,
                                               u16* __restrict__ vvT) {
  __shared__ u16 t[32][36];
  const int tid = threadIdx.x;
  const int bh = blockIdx.z, b = bh >> 3, h = bh & 7;
  const int i0 = blockIdx.x * 32, d0 = blockIdx.y * 32;
  const int r = tid >> 3, c4 = (tid & 7) * 4;
  union { u16 u[4]; uint2 v; } p;
  p.v = *(const uint2*)(vvb + (size_t)(b * KK + i0 + r) * NH + h * DK + d0 + c4);
  t[r][c4 + 0] = p.u[0];
  t[r][c4 + 1] = p.u[1];
  t[r][c4 + 2] = p.u[2];
  t[r][c4 + 3] = p.u[3];
  __syncthreads();
#pragma unroll
  for (int i = 0; i < 4; i++) p.u[i] = t[c4 + i][r];
  *(uint2*)(vvT + (size_t)(bh * DK + d0 + r) * KK + i0 + c4) = p.v;
}

// ---------------- generic MFMA GEMM: C = A[M,Kd] * Bt[N,Kd]^T (+bias) ---------------
// A is f32 (cast during staging) or bf16. Bt rows are k-contiguous bf16.
// Tile 128x128x32, 4 waves in 2x2, each wave 64x64 via 4x4 16x16x32 MFMA tiles.
template <bool A_BF16>
__global__ __launch_bounds__(256, 2) void gemm_bt(
    const void* __restrict__ Av, const u16* __restrict__ Bt,
    const float* __restrict__ bias, u16* __restrict__ Cb, float* __restrict__ Cf,
    int Kd, int ldc, long long aBatch, long long btBatch,
    long long cBatchB, long long cBatchH) {
  __shared__ __align__(16) u16 As[128 * 40];
  __shared__ __align__(16) u16 Bs[128 * 40];
  const int tid = threadIdx.x;
  const int z = blockIdx.z;
  const int nBase = blockIdx.x * 128;
  const int mBase = blockIdx.y * 128;
  const float* Af = (const float*)Av + (size_t)z * aBatch;
  const u16* Ah = (const u16*)Av + (size_t)z * aBatch;
  const u16* Bb = Bt + (size_t)z * btBatch;
  const size_t cOff = (size_t)(z >> 3) * cBatchB + (size_t)(z & 7) * cBatchH;

  const int wid = tid >> 6, lane = tid & 63;
  const int wm = (wid & 1) * 64, wn = (wid >> 1) * 64;
  const int lm = lane & 15, lq = lane >> 4;
  const int sRow = tid >> 1;          // staging: 2 threads per row
  const int sCol = (tid & 1) * 16;    // 16 k-elems each

  floatx4 acc[4][4] = {};

  for (int k0 = 0; k0 < Kd; k0 += 32) {
    union { u16 u[8]; uint4 v; } pa0, pa1;
    if (A_BF16) {
      const u16* ap = Ah + (size_t)(mBase + sRow) * Kd + k0 + sCol;
      pa0.v = *(const uint4*)ap;
      pa1.v = *(const uint4*)(ap + 8);
    } else {
      const float* ap = Af + (size_t)(mBase + sRow) * Kd + k0 + sCol;
      float4 f0 = *(const float4*)(ap + 0);
      float4 f1 = *(const float4*)(ap + 4);
      float4 f2 = *(const float4*)(ap + 8);
      float4 f3 = *(const float4*)(ap + 12);
      pa0.u[0] = f2bf(f0.x); pa0.u[1] = f2bf(f0.y);
      pa0.u[2] = f2bf(f0.z); pa0.u[3] = f2bf(f0.w);
      pa0.u[4] = f2bf(f1.x); pa0.u[5] = f2bf(f1.y);
      pa0.u[6] = f2bf(f1.z); pa0.u[7] = f2bf(f1.w);
      pa1.u[0] = f2bf(f2.x); pa1.u[1] = f2bf(f2.y);
      pa1.u[2] = f2bf(f2.z); pa1.u[3] = f2bf(f2.w);
      pa1.u[4] = f2bf(f3.x); pa1.u[5] = f2bf(f3.y);
      pa1.u[6] = f2bf(f3.z); pa1.u[7] = f2bf(f3.w);
    }
    const u16* bp = Bb + (size_t)(nBase + sRow) * Kd + k0 + sCol;
    uint4 pb0 = *(const uint4*)bp;
    uint4 pb1 = *(const uint4*)(bp + 8);

    *(uint4*)&As[sRow * 40 + sCol + 0] = pa0.v;
    *(uint4*)&As[sRow * 40 + sCol + 8] = pa1.v;
    *(uint4*)&Bs[sRow * 40 + sCol + 0] = pb0;
    *(uint4*)&Bs[sRow * 40 + sCol + 8] = pb1;
    __syncthreads();

    short8 af[4], bfr[4];
#pragma unroll
    for (int t = 0; t < 4; t++) {
      af[t]  = *(const short8*)&As[(wm + t * 16 + lm) * 40 + lq * 8];
      bfr[t] = *(const short8*)&Bs[(wn + t * 16 + lm) * 40 + lq * 8];
    }
#pragma unroll
    for (int i = 0; i < 4; i++)
#pragma unroll
      for (int j = 0; j < 4; j++)
        acc[i][j] = MFMA16(af[i], bfr[j], acc[i][j]);
    __syncthreads();
  }

  // epilogue: C/D layout col=lane&15, row=(lane>>4)*4+reg
#pragma unroll
  for (int i = 0; i < 4; i++) {
    const int rowL = wm + i * 16 + lq * 4;
#pragma unroll
    for (int j = 0; j < 4; j++) {
      const int col = nBase + wn + j * 16 + lm;
      const float bval = bias ? bias[col] : 0.0f;
      const size_t base = cOff + (size_t)(mBase + rowL) * ldc + col;
#pragma unroll
      for (int r = 0; r < 4; r++) {
        const float v = acc[i][j][r] + bval;
        if (Cb) Cb[base + (size_t)r * ldc] = f2bf(v);
        if (Cf) Cf[base + (size_t)r * ldc] = v;
      }
    }
  }
}

// ---------------- fused scores + mask + softmax -> att (f32) ------------------------
// Block: one (b,h), 16 query rows, full 1024 keys. 4 waves x 256-col slices.
// Scores live entirely in registers (acc[16]); softmax reduces over the 16-lane
// col dimension via shuffles, cross-wave via tiny LDS.
__global__ __launch_bounds__(256, 2) void scores_softmax(
    const u16* __restrict__ qb, const u16* __restrict__ kb,
    const int* __restrict__ mask, float* __restrict__ att) {
  __shared__ int msk[1024];
  __shared__ float redM[4][16];
  __shared__ float redS[4][16];
  const int tid = threadIdx.x;
  const int rowBlk = blockIdx.x, bh = blockIdx.y;
  const int b = bh >> 3, h = bh & 7;
  const int wid = tid >> 6, lane = tid & 63;
  const int lm = lane & 15, lq = lane >> 4;
  const int rowG = rowBlk * 16;

  *(int4*)&msk[tid * 4] = *(const int4*)(mask + (size_t)b * KK + tid * 4);

  // q fragments: 16 rows x dk=128 (4 k-steps), held in regs
  short8 qf[4];
  const u16* qp = qb + (size_t)(b * KK + rowG + lm) * NH + h * DK + lq * 8;
#pragma unroll
  for (int ks = 0; ks < 4; ks++) qf[ks] = *(const short8*)(qp + ks * 32);

  floatx4 acc[16] = {};
  const u16* kpB = kb + (size_t)(b * KK + wid * 256 + lm) * NH + h * DK + lq * 8;
#pragma unroll
  for (int jt = 0; jt < 16; jt++) {
    const u16* kp = kpB + (size_t)jt * 16 * NH;
    short8 k0 = *(const short8*)(kp + 0);
    short8 k1 = *(const short8*)(kp + 32);
    short8 k2 = *(const short8*)(kp + 64);
    short8 k3 = *(const short8*)(kp + 96);
    floatx4 a = acc[jt];
    a = MFMA16(qf[0], k0, a);
    a = MFMA16(qf[1], k1, a);
    a = MFMA16(qf[2], k2, a);
    a = MFMA16(qf[3], k3, a);
    acc[jt] = a;
  }
  __syncthreads();  // msk stores complete

  const float scale = 0.08838834764831845f;  // 1/sqrt(128)
  float mrow[4] = {-3e38f, -3e38f, -3e38f, -3e38f};
#pragma unroll
  for (int jt = 0; jt < 16; jt++) {
    const int col = wid * 256 + jt * 16 + lm;
    const bool mk = msk[col] != 0;
#pragma unroll
    for (int r = 0; r < 4; r++) {
      float s = mk ? -1e9f : acc[jt][r] * scale;
      acc[jt][r] = s;
      mrow[r] = fmaxf(mrow[r], s);
    }
  }
  // reduce max over the 16 lanes holding this row's cols
#pragma unroll
  for (int off = 1; off < 16; off <<= 1)
#pragma unroll
    for (int r = 0; r < 4; r++) mrow[r] = fmaxf(mrow[r], __shfl_xor(mrow[r], off));
  if (lm == 0) {
#pragma unroll
    for (int r = 0; r < 4; r++) redM[wid][lq * 4 + r] = mrow[r];
  }
  __syncthreads();
#pragma unroll
  for (int r = 0; r < 4; r++)
    mrow[r] = fmaxf(fmaxf(redM[0][lq * 4 + r], redM[1][lq * 4 + r]),
                    fmaxf(redM[2][lq * 4 + r], redM[3][lq * 4 + r]));

  float srow[4] = {0.f, 0.f, 0.f, 0.f};
#pragma unroll
  for (int jt = 0; jt < 16; jt++)
#pragma unroll
    for (int r = 0; r < 4; r++) {
      float e = __expf(acc[jt][r] - mrow[r]);
      acc[jt][r] = e;
      srow[r] += e;
    }
#pragma unroll
  for (int off = 1; off < 16; off <<= 1)
#pragma unroll
    for (int r = 0; r < 4; r++) srow[r] += __shfl_xor(srow[r], off);
  if (lm == 0) {
#pragma unroll
    for (int r = 0; r < 4; r++) redS[wid][lq * 4 + r] = srow[r];
  }
  __syncthreads();
#pragma unroll
  for (int r = 0; r < 4; r++) {
    float s = redS[0][lq * 4 + r] + redS[1][lq * 4 + r] +
              redS[2][lq * 4 + r] + redS[3][lq * 4 + r];
    srow[r] = 1.0f / s;
  }
#pragma unroll
  for (int jt = 0; jt < 16; jt++) {
    const int col = wid * 256 + jt * 16 + lm;
#pragma unroll
    for (int r = 0; r < 4; r++) {
      const int row = lq * 4 + r;
      att[((size_t)bh * KK + rowG + row) * KK + col] = acc[jt][r] * srow[r];
    }
  }
}

// ---------------- launcher ----------------------------------------------------------
extern "C" void kernel_launch(void* const* d_in, const int* in_sizes, int n_in,
                              void* d_out, int out_size, void* d_ws, size_t ws_size,
                              hipStream_t stream) {
  const float* v     = (const float*)d_in[0];
  const float* key   = (const float*)d_in[1];
  const float* query = (const float*)d_in[2];
  const int*   mask  = (const int*)d_in[3];
  const float* Wq = (const float*)d_in[4];
  const float* bq = (const float*)d_in[5];
  const float* Wk = (const float*)d_in[6];
  const float* bk = (const float*)d_in[7];
  const float* Wv = (const float*)d_in[8];
  const float* bv = (const float*)d_in[9];
  const float* Wm = (const float*)d_in[10];
  const float* bm = (const float*)d_in[11];

  float* atted = (float*)d_out;
  float* att   = atted + (size_t)ATT_OFF;

  // workspace layout (bytes): needs ~168 MB
  char* ws = (char*)d_ws;
  u16* qb   = (u16*)(ws + 0);
  u16* kb   = (u16*)(ws + 33554432ll);
  u16* vvb  = (u16*)(ws + 67108864ll);
  u16* vvT  = (u16*)(ws + 100663296ll);
  u16* atp  = (u16*)(ws + 134217728ll);
  u16* WqT  = (u16*)(ws + 167772160ll);
  u16* WkT  = (u16*)(ws + 169869312ll);
  u16* WvT  = (u16*)(ws + 171966464ll);
  u16* WmT  = (u16*)(ws + 174063616ll);

  // 1) weight transposes (f32 -> bf16, [k][n] -> [n][k])
  tr_w<<<dim3(32, 32), 256, 0, stream>>>(Wq, WqT);
  tr_w<<<dim3(32, 32), 256, 0, stream>>>(Wk, WkT);
  tr_w<<<dim3(32, 32), 256, 0, stream>>>(Wv, WvT);
  tr_w<<<dim3(32, 32), 256, 0, stream>>>(Wm, WmT);

  // 2) projections: [16384,1024] x [1024,1024] -> bf16
  gemm_bt<false><<<dim3(8, 128, 1), 256, 0, stream>>>(query, WqT, bq, qb, nullptr,
                                                      1024, 1024, 0, 0, 0, 0);
  gemm_bt<false><<<dim3(8, 128, 1), 256, 0, stream>>>(key, WkT, bk, kb, nullptr,
                                                      1024, 1024, 0, 0, 0, 0);
  gemm_bt<false><<<dim3(8, 128, 1), 256, 0, stream>>>(v, WvT, bv, vvb, nullptr,
                                                      1024, 1024, 0, 0, 0, 0);

  // 3) vv -> vvT[bh][d][k]
  tr_head<<<dim3(32, 4, 128), 256, 0, stream>>>(vvb, vvT);

  // 4) scores + mask + softmax -> att (f32, d_out)
  scores_softmax<<<dim3(64, 128), 256, 0, stream>>>(qb, kb, mask, att);

  // 5) att @ vv  (batched over bh=128): [1024,1024] x [1024,128] -> atp bf16
  gemm_bt<false><<<dim3(1, 8, 128), 256, 0, stream>>>(att, vvT, nullptr, atp, nullptr,
                                                      1024, 1024,
                                                      1048576ll, 131072ll,
                                                      1048576ll, 128ll);

  // 6) output projection: atp bf16 [16384,1024] x WmT -> atted f32
  gemm_bt<true><<<dim3(8, 128, 1), 256, 0, stream>>>(atp, WmT, bm, nullptr, atted,
                                                     1024, 1024, 0, 0, 0, 0);
}